// Round 13
// baseline (193.162 us; speedup 1.0000x reference)
//
#include <hip/hip_runtime.h>
#include <math.h>

constexpr int NN     = 100000;
constexpr int E_BASE = 1600000;
constexpr int E_TOT  = E_BASE + NN;   // self-loops appended
constexpr int F_IN   = 128;
constexpr int F1     = 64;            // H1*C1
constexpr int H1n    = 8;
constexpr int F2     = 40;            // layer-2 out (H=1)

// bucketed CSR build geometry
constexpr int BSHIFT    = 9;                      // 512 nodes per bucket
constexpr int NB        = (NN + 511) >> BSHIFT;   // 196 buckets
constexpr int BCAP      = 12288;
constexpr int P1_BLOCKS = 256;
constexpr int EPB       = (E_TOT + P1_BLOCKS - 1) / P1_BLOCKS;   // 6641
constexpr int L1_BLOCKS = (NN + 63) / 64;                        // 1563

__device__ __forceinline__ float lrelu(float v) { return fmaxf(v, 0.2f * v); }

__device__ __forceinline__ unsigned bpack(float a, float b) {
    unsigned ua = __float_as_uint(a) + 0x8000u;
    unsigned ub = __float_as_uint(b) + 0x8000u;
    return (ua >> 16) | (ub & 0xFFFF0000u);
}
__device__ __forceinline__ float blo(unsigned u) { return __uint_as_float(u << 16); }
__device__ __forceinline__ float bhi(unsigned u) { return __uint_as_float(u & 0xFFFF0000u); }

// ---------------- fused: layer-1 GEMM (+logits) ∪ edge partition ----------
__global__ __launch_bounds__(256) void fused_l1p(const float* __restrict__ x,
                                                 const float* __restrict__ W1,
                                                 const float* __restrict__ a_src,
                                                 const float* __restrict__ a_dst,
                                                 unsigned* __restrict__ h1b,
                                                 float* __restrict__ as1,
                                                 float* __restrict__ ad1,
                                                 const int* __restrict__ src,
                                                 const int* __restrict__ dst,
                                                 int* __restrict__ bucket_cnt,
                                                 unsigned* __restrict__ store) {
    __shared__ __align__(16) unsigned char smraw[17408];
    int t = threadIdx.x;
    if (blockIdx.x < L1_BLOCKS) {
        float (*xs)[36] = (float(*)[36])smraw;           // [64][36]
        float* wsld     = (float*)(smraw + 9216);        // [2048]
        int nb = blockIdx.x * 64;
        int ct = t & 15, nt = t >> 4;
        int rs = t >> 3, qs = t & 7;
        float acc[4][4] = {};
        for (int K0 = 0; K0 < F_IN; K0 += 32) {
            int r0 = min(nb + rs, NN - 1);
            int r1 = min(nb + rs + 32, NN - 1);
            float4 v0 = *(const float4*)&x[(size_t)r0 * F_IN + K0 + qs * 4];
            float4 v1 = *(const float4*)&x[(size_t)r1 * F_IN + K0 + qs * 4];
            *(float4*)&xs[rs][qs * 4] = v0;
            *(float4*)&xs[rs + 32][qs * 4] = v1;
            const float4* wsrc = (const float4*)&W1[(size_t)K0 * F1];
            *(float4*)&wsld[t * 4] = wsrc[t];
            *(float4*)&wsld[1024 + t * 4] = wsrc[256 + t];
            __syncthreads();
#pragma unroll 8
            for (int kk = 0; kk < 32; ++kk) {
                float4 w = *(const float4*)&wsld[kk * 64 + ct * 4];
                float x0 = xs[nt * 4 + 0][kk];
                float x1 = xs[nt * 4 + 1][kk];
                float x2 = xs[nt * 4 + 2][kk];
                float x3 = xs[nt * 4 + 3][kk];
                acc[0][0] = fmaf(x0, w.x, acc[0][0]); acc[0][1] = fmaf(x0, w.y, acc[0][1]);
                acc[0][2] = fmaf(x0, w.z, acc[0][2]); acc[0][3] = fmaf(x0, w.w, acc[0][3]);
                acc[1][0] = fmaf(x1, w.x, acc[1][0]); acc[1][1] = fmaf(x1, w.y, acc[1][1]);
                acc[1][2] = fmaf(x1, w.z, acc[1][2]); acc[1][3] = fmaf(x1, w.w, acc[1][3]);
                acc[2][0] = fmaf(x2, w.x, acc[2][0]); acc[2][1] = fmaf(x2, w.y, acc[2][1]);
                acc[2][2] = fmaf(x2, w.z, acc[2][2]); acc[2][3] = fmaf(x2, w.w, acc[2][3]);
                acc[3][0] = fmaf(x3, w.x, acc[3][0]); acc[3][1] = fmaf(x3, w.y, acc[3][1]);
                acc[3][2] = fmaf(x3, w.z, acc[3][2]); acc[3][3] = fmaf(x3, w.w, acc[3][3]);
            }
            __syncthreads();
        }
        float4 as4 = ((const float4*)a_src)[ct];
        float4 ds4 = ((const float4*)a_dst)[ct];
#pragma unroll
        for (int i = 0; i < 4; ++i) {
            int n = nb + nt * 4 + i;
            unsigned u0 = bpack(acc[i][0], acc[i][1]);
            unsigned u1 = bpack(acc[i][2], acc[i][3]);
            float ps = acc[i][0]*as4.x + acc[i][1]*as4.y + acc[i][2]*as4.z + acc[i][3]*as4.w;
            float pd = acc[i][0]*ds4.x + acc[i][1]*ds4.y + acc[i][2]*ds4.z + acc[i][3]*ds4.w;
            ps += __shfl_xor(ps, 1, 64);
            pd += __shfl_xor(pd, 1, 64);
            if (n < NN) {
                *(uint2*)&h1b[(size_t)n * 32 + ct * 2] = make_uint2(u0, u1);
                if (!(ct & 1)) {
                    as1[n * H1n + (ct >> 1)] = ps;
                    ad1[n * H1n + (ct >> 1)] = pd;
                }
            }
        }
    } else {
        int* bins  = (int*)smraw;
        int* basep = (int*)(smraw + NB * 4);
        for (int i = t; i < NB; i += 256) bins[i] = 0;
        __syncthreads();
        int pb = blockIdx.x - L1_BLOCKS;
        int e0 = pb * EPB;
        int e1 = min(e0 + EPB, E_TOT);
        for (int e = e0 + t; e < e1; e += 256) {
            int d = (e < E_BASE) ? dst[e] : (e - E_BASE);
            atomicAdd(&bins[d >> BSHIFT], 1);
        }
        __syncthreads();
        for (int i = t; i < NB; i += 256) {
            basep[i] = atomicAdd(&bucket_cnt[i], bins[i]);
            bins[i] = 0;
        }
        __syncthreads();
        for (int e = e0 + t; e < e1; e += 256) {
            int s, d;
            if (e < E_BASE) { s = src[e]; d = dst[e]; }
            else            { s = e - E_BASE; d = s; }
            int b = d >> BSHIFT;
            int p = atomicAdd(&bins[b], 1);
            store[(size_t)b * BCAP + basep[b] + p] = ((unsigned)s << 9) | (unsigned)(d & 511);
        }
    }
}

// per-bucket CSR with inline prefix over bucket_cnt
__global__ __launch_bounds__(256) void bucket_csr(const int* __restrict__ bucket_cnt,
                                                  const unsigned* __restrict__ store,
                                                  int* __restrict__ row_start,
                                                  int* __restrict__ csr_src) {
    __shared__ int cnt_l[512];
    __shared__ int incl[512];
    __shared__ int cur_l[512];
    __shared__ int sh_gbase;
    int b = blockIdx.x;
    int t = threadIdx.x;
    int cnt = bucket_cnt[b];
    int nlo = b << BSHIFT;
    int nodes = min(512, NN - nlo);
    cnt_l[t] = 0; cnt_l[t + 256] = 0;
    if (t < 64) {
        int partial = 0;
        for (int i = t; i < NB; i += 64)
            if (i < b) partial += bucket_cnt[i];
#pragma unroll
        for (int m = 1; m < 64; m <<= 1) partial += __shfl_xor(partial, m, 64);
        if (t == 0) {
            sh_gbase = partial;
            if (b == NB - 1) row_start[NN] = partial + cnt;
        }
    }
    __syncthreads();
    int gbase = sh_gbase;
    const unsigned* sp = store + (size_t)b * BCAP;
    for (int i = t; i < cnt; i += 256)
        atomicAdd(&cnt_l[sp[i] & 511], 1);
    __syncthreads();
    if (t < 64) {
        int run = 0;
        for (int c = 0; c < 512; c += 64) {
            int v = cnt_l[c + t];
#pragma unroll
            for (int off = 1; off < 64; off <<= 1) {
                int u = __shfl_up(v, off, 64);
                if (t >= off) v += u;
            }
            incl[c + t] = run + v;
            run = __shfl(run + v, 63, 64);
        }
    }
    __syncthreads();
    for (int j = t; j < 512; j += 256) {
        int start = gbase + incl[j] - cnt_l[j];
        cur_l[j] = start;
        if (j < nodes) row_start[nlo + j] = start;
    }
    __syncthreads();
    for (int i = t; i < cnt; i += 256) {
        unsigned ed = sp[i];
        int p = atomicAdd(&cur_l[ed & 511], 1);
        csr_src[p] = (int)(ed >> 9);
    }
}

// ---------------- layer 1 softmax+aggregate -------------------------------
// 2 independent waves/block (node = bid*2 + wid); deep pipeline: next
// chunk's {csr, logit, 4 h1b rows} issued before current chunk's math.
__global__ __launch_bounds__(128) void node_agg1(const int* __restrict__ row_start,
                                                 const int* __restrict__ csr_src,
                                                 const float* __restrict__ as1,
                                                 const float* __restrict__ ad1,
                                                 const unsigned* __restrict__ h1b,
                                                 const float* __restrict__ b1,
                                                 float* __restrict__ out1r) {
    int n = blockIdx.x * 2 + (threadIdx.x >> 6);
    if (n >= NN) return;
    int lane = threadIdx.x & 63;
    int e8 = lane & 7, hp = lane >> 3;        // p-phase coords
    int il = lane & 31, q = lane >> 5;        // acc coords
    int hc = il >> 2;
    float adv = ad1[(unsigned)n * 8u + (unsigned)hp];
    int lo = row_start[n], hi = row_start[n + 1];
    float ssum = 0.f, acc0 = 0.f, acc1 = 0.f;
    int   s_cur = csr_src[(unsigned)min(lo + e8, hi - 1)];
    float g_cur = as1[(unsigned)s_cur * 8u + (unsigned)hp];
    unsigned u_cur[4];
#pragma unroll
    for (int j = 0; j < 4; ++j) {
        int sb = __shfl(s_cur, 2 * j + q, 64);
        u_cur[j] = h1b[(unsigned)sb * 32u + (unsigned)il];
    }
    for (int base = lo; base < hi; base += 8) {
        int s_nxt = s_cur; float g_nxt = 0.f;
        unsigned u_nxt[4];
        bool more = (base + 8) < hi;           // wave-uniform
        if (more) {
            s_nxt = csr_src[(unsigned)min(base + 8 + e8, hi - 1)];
            g_nxt = as1[(unsigned)s_nxt * 8u + (unsigned)hp];
#pragma unroll
            for (int j = 0; j < 4; ++j) {
                int sb = __shfl(s_nxt, 2 * j + q, 64);
                u_nxt[j] = h1b[(unsigned)sb * 32u + (unsigned)il];
            }
        }
        float v = lrelu(g_cur + adv);
        float p = (base + e8 < hi) ? __expf(v) : 0.f;
        ssum += p;
#pragma unroll
        for (int j = 0; j < 4; ++j) {
            float pb = __shfl(p, (hc << 3) | (2 * j + q), 64);
            acc0 = fmaf(pb, blo(u_cur[j]), acc0);
            acc1 = fmaf(pb, bhi(u_cur[j]), acc1);
        }
        s_cur = s_nxt; g_cur = g_nxt;
#pragma unroll
        for (int j = 0; j < 4; ++j) u_cur[j] = u_nxt[j];
    }
    ssum += __shfl_xor(ssum, 1, 64);
    ssum += __shfl_xor(ssum, 2, 64);
    ssum += __shfl_xor(ssum, 4, 64);
    float sh = __shfl(ssum, hc << 3, 64);
    float p0 = acc0 + __shfl(acc0, il | 32, 64);
    float p1 = acc1 + __shfl(acc1, il | 32, 64);
    if (lane < 32) {
        float r = 1.f / (sh + 1e-16f);
        float2 bv = ((const float2*)b1)[il];
        float2 o;
        o.x = fmaxf(fmaf(p0, r, bv.x), 0.f);
        o.y = fmaxf(fmaf(p1, r, bv.y), 0.f);
        ((float2*)(out1r + (size_t)n * F1))[il] = o;
    }
}

// ---------------- layer 2 GEMM: h2a/h2c(bf16) = out1r @ W2, fused logits --
__global__ __launch_bounds__(256) void linear2(const float* __restrict__ out1r,
                                               const float* __restrict__ W2,
                                               const float* __restrict__ a_src2,
                                               const float* __restrict__ a_dst2,
                                               unsigned* __restrict__ h2a,
                                               unsigned* __restrict__ h2c,
                                               float* __restrict__ as2,
                                               float* __restrict__ ad2) {
    __shared__ float xs[128][65];
    __shared__ float ws[64 * 40];
    int t = threadIdx.x;
    int nb = blockIdx.x * 128;
    int colq = t & 15, rr = t >> 4;
#pragma unroll
    for (int i = 0; i < 8; ++i) {
        int r = rr + 16 * i;
        int g = min(nb + r, NN - 1);
        float4 v = *(const float4*)&out1r[(size_t)g * F1 + colq * 4];
        xs[r][colq * 4 + 0] = v.x; xs[r][colq * 4 + 1] = v.y;
        xs[r][colq * 4 + 2] = v.z; xs[r][colq * 4 + 3] = v.w;
    }
#pragma unroll
    for (int i = 0; i < 10; ++i) ws[t + 256 * i] = W2[t + 256 * i];
    __syncthreads();
    int ct = t & 7, nt = t >> 3;
    float acc[4][5] = {};
#pragma unroll 4
    for (int k = 0; k < F1; ++k) {
        float w0 = ws[k * 40 + ct * 5 + 0];
        float w1 = ws[k * 40 + ct * 5 + 1];
        float w2 = ws[k * 40 + ct * 5 + 2];
        float w3 = ws[k * 40 + ct * 5 + 3];
        float w4 = ws[k * 40 + ct * 5 + 4];
#pragma unroll
        for (int i = 0; i < 4; ++i) {
            float xv = xs[nt * 4 + i][k];
            acc[i][0] = fmaf(xv, w0, acc[i][0]);
            acc[i][1] = fmaf(xv, w1, acc[i][1]);
            acc[i][2] = fmaf(xv, w2, acc[i][2]);
            acc[i][3] = fmaf(xv, w3, acc[i][3]);
            acc[i][4] = fmaf(xv, w4, acc[i][4]);
        }
    }
    float aw[5], dw[5];
#pragma unroll
    for (int j = 0; j < 5; ++j) { aw[j] = a_src2[ct * 5 + j]; dw[j] = a_dst2[ct * 5 + j]; }
#pragma unroll
    for (int i = 0; i < 4; ++i) {
        int n = nb + nt * 4 + i;
        float vs = acc[i][0]*aw[0] + acc[i][1]*aw[1] + acc[i][2]*aw[2]
                 + acc[i][3]*aw[3] + acc[i][4]*aw[4];
        float vd = acc[i][0]*dw[0] + acc[i][1]*dw[1] + acc[i][2]*dw[2]
                 + acc[i][3]*dw[3] + acc[i][4]*dw[4];
        vs += __shfl_xor(vs, 1, 64); vs += __shfl_xor(vs, 2, 64); vs += __shfl_xor(vs, 4, 64);
        vd += __shfl_xor(vd, 1, 64); vd += __shfl_xor(vd, 2, 64); vd += __shfl_xor(vd, 4, 64);
        if (n < NN && ct == 0) { as2[n] = vs; ad2[n] = vd; }
    }
    __syncthreads();
#pragma unroll
    for (int i = 0; i < 4; ++i) {
        int r = nt * 4 + i;
#pragma unroll
        for (int j = 0; j < 5; ++j) xs[r][ct * 5 + j] = acc[i][j];
    }
    __syncthreads();
    {
        int r = t >> 1, half = t & 1;
        int n = nb + r;
        if (n < NN) {
#pragma unroll
            for (int k = 0; k < 10; ++k) {
                int w = half * 10 + k;
                unsigned val = bpack(xs[r][2 * w], xs[r][2 * w + 1]);
                if (w < 16) h2a[(size_t)n * 16 + w] = val;
                else        h2c[(size_t)n * 4 + (w - 16)] = val;
            }
        }
    }
}

// ---------------- layer 2 softmax+aggregate (+b2) -------------------------
// 2 independent waves/block; deep pipeline; uniform h2 base + 32-bit
// per-lane offset (h2a/h2c contiguous).
__global__ __launch_bounds__(128) void node_agg2(const int* __restrict__ row_start,
                                                 const int* __restrict__ csr_src,
                                                 const float* __restrict__ as2,
                                                 const float* __restrict__ ad2,
                                                 const unsigned* __restrict__ h2,
                                                 const float* __restrict__ b2,
                                                 float* __restrict__ out) {
    int n = blockIdx.x * 2 + (threadIdx.x >> 6);
    if (n >= NN) return;
    int lane = threadIdx.x & 63;
    int e8 = lane & 7;
    int il = lane & 31, q = lane >> 5;
    bool act = il < 20;
    unsigned gstride = (il < 16) ? 16u : ((il < 20) ? 4u : 0u);
    unsigned gofs    = (il < 16) ? (unsigned)il
                     : ((il < 20) ? (unsigned)(NN * 16 + (il - 16)) : 0u);
    float adv = ad2[n];
    int lo = row_start[n], hi = row_start[n + 1];
    float ssum = 0.f, acc0 = 0.f, acc1 = 0.f;
    int   s_cur = csr_src[(unsigned)min(lo + e8, hi - 1)];
    float g_cur = as2[(unsigned)s_cur];
    unsigned u_cur[4];
#pragma unroll
    for (int j = 0; j < 4; ++j) {
        int sb = __shfl(s_cur, 2 * j + q, 64);
        u_cur[j] = h2[(unsigned)sb * gstride + gofs];
    }
    for (int base = lo; base < hi; base += 8) {
        int s_nxt = s_cur; float g_nxt = 0.f;
        unsigned u_nxt[4];
        bool more = (base + 8) < hi;           // wave-uniform
        if (more) {
            s_nxt = csr_src[(unsigned)min(base + 8 + e8, hi - 1)];
            g_nxt = as2[(unsigned)s_nxt];
#pragma unroll
            for (int j = 0; j < 4; ++j) {
                int sb = __shfl(s_nxt, 2 * j + q, 64);
                u_nxt[j] = h2[(unsigned)sb * gstride + gofs];
            }
        }
        float v = lrelu(g_cur + adv);
        float p = (base + e8 < hi) ? __expf(v) : 0.f;
        ssum += p;
#pragma unroll
        for (int j = 0; j < 4; ++j) {
            float pb = __shfl(p, 2 * j + q, 64);
            acc0 = fmaf(pb, blo(u_cur[j]), acc0);
            acc1 = fmaf(pb, bhi(u_cur[j]), acc1);
        }
        s_cur = s_nxt; g_cur = g_nxt;
#pragma unroll
        for (int j = 0; j < 4; ++j) u_cur[j] = u_nxt[j];
    }
    ssum += __shfl_xor(ssum, 1, 64);
    ssum += __shfl_xor(ssum, 2, 64);
    ssum += __shfl_xor(ssum, 4, 64);
    float p0 = acc0 + __shfl(acc0, il | 32, 64);
    float p1 = acc1 + __shfl(acc1, il | 32, 64);
    if (lane < 32 && act) {
        float r = 1.f / (ssum + 1e-16f);
        float2 bv = ((const float2*)b2)[il];
        float2 o;
        o.x = fmaf(p0, r, bv.x);
        o.y = fmaf(p1, r, bv.y);
        ((float2*)(out + (size_t)n * F2))[il] = o;
    }
}

extern "C" void kernel_launch(void* const* d_in, const int* in_sizes, int n_in,
                              void* d_out, int out_size, void* d_ws, size_t ws_size,
                              hipStream_t stream) {
    const float* x      = (const float*)d_in[0];
    const int*   ei     = (const int*)d_in[1];
    const float* W1     = (const float*)d_in[2];
    const float* a_src1 = (const float*)d_in[3];
    const float* a_dst1 = (const float*)d_in[4];
    const float* b1     = (const float*)d_in[5];
    const float* W2     = (const float*)d_in[6];
    const float* a_src2 = (const float*)d_in[7];
    const float* a_dst2 = (const float*)d_in[8];
    const float* b2     = (const float*)d_in[9];
    float* out = (float*)d_out;
    const int* srcp = ei;            // edge_index[0]
    const int* dstp = ei + E_BASE;   // edge_index[1]

    unsigned* h1b        = (unsigned*)d_ws;                      // N*32 uints
    unsigned* storeu     = h1b + (size_t)NN * 32;                // NB*BCAP uints
    float*    as1        = (float*)(storeu + (size_t)NB * BCAP); // N*8
    float*    ad1        = as1 + (size_t)NN * H1n;               // N*8
    float*    out1r      = ad1 + (size_t)NN * H1n;               // N*64
    unsigned* h2a        = (unsigned*)(out1r + (size_t)NN * F1); // N*16 uints
    unsigned* h2c        = h2a + (size_t)NN * 16;                // N*4 uints (contiguous)
    float*    as2        = (float*)(h2c + (size_t)NN * 4);       // N
    float*    ad2        = as2 + NN;                             // N
    int*      row_start  = (int*)(ad2 + NN);                     // N+1
    int*      csr_src    = row_start + (NN + 1);                 // E_TOT
    int*      bucket_cnt = csr_src + E_TOT;                      // NB

    hipMemsetAsync(bucket_cnt, 0, NB * sizeof(int), stream);

    fused_l1p<<<L1_BLOCKS + P1_BLOCKS, 256, 0, stream>>>(
        x, W1, a_src1, a_dst1, h1b, as1, ad1, srcp, dstp, bucket_cnt, storeu);
    bucket_csr<<<NB, 256, 0, stream>>>(bucket_cnt, storeu, row_start, csr_src);

    node_agg1<<<(NN + 1) / 2, 128, 0, stream>>>(row_start, csr_src, as1, ad1, h1b, b1, out1r);

    linear2<<<(NN + 127) / 128, 256, 0, stream>>>(out1r, W2, a_src2, a_dst2, h2a, h2c, as2, ad2);
    node_agg2<<<(NN + 1) / 2, 128, 0, stream>>>(row_start, csr_src, as2, ad2, h2a, b2, out);
}

// Round 14
// 191.183 us; speedup vs baseline: 1.0104x; 1.0104x over previous
//
#include <hip/hip_runtime.h>
#include <math.h>

constexpr int NN     = 100000;
constexpr int E_BASE = 1600000;
constexpr int E_TOT  = E_BASE + NN;   // self-loops appended
constexpr int F_IN   = 128;
constexpr int F1     = 64;            // H1*C1
constexpr int H1n    = 8;
constexpr int F2     = 40;            // layer-2 out (H=1)

// bucketed CSR build geometry
constexpr int BSHIFT    = 9;                      // 512 nodes per bucket
constexpr int NB        = (NN + 511) >> BSHIFT;   // 196 buckets
constexpr int BCAP      = 12288;
constexpr int P1_BLOCKS = 256;
constexpr int EPB       = (E_TOT + P1_BLOCKS - 1) / P1_BLOCKS;   // 6641
constexpr int L1_BLOCKS = (NN + 63) / 64;                        // 1563

constexpr unsigned HC_BASE = (unsigned)NN * 16u;  // h2cx offset within h2 pool

__device__ __forceinline__ float lrelu(float v) { return fmaxf(v, 0.2f * v); }

__device__ __forceinline__ unsigned bpack(float a, float b) {
    unsigned ua = __float_as_uint(a) + 0x8000u;
    unsigned ub = __float_as_uint(b) + 0x8000u;
    return (ua >> 16) | (ub & 0xFFFF0000u);
}
__device__ __forceinline__ float blo(unsigned u) { return __uint_as_float(u << 16); }
__device__ __forceinline__ float bhi(unsigned u) { return __uint_as_float(u & 0xFFFF0000u); }

// ---------------- fused: layer-1 GEMM (+logits) ∪ edge partition ----------
__global__ __launch_bounds__(256) void fused_l1p(const float* __restrict__ x,
                                                 const float* __restrict__ W1,
                                                 const float* __restrict__ a_src,
                                                 const float* __restrict__ a_dst,
                                                 unsigned* __restrict__ h1b,
                                                 float* __restrict__ as1,
                                                 float* __restrict__ ad1,
                                                 const int* __restrict__ src,
                                                 const int* __restrict__ dst,
                                                 int* __restrict__ bucket_cnt,
                                                 unsigned* __restrict__ store) {
    __shared__ __align__(16) unsigned char smraw[17408];
    int t = threadIdx.x;
    if (blockIdx.x < L1_BLOCKS) {
        float (*xs)[36] = (float(*)[36])smraw;           // [64][36]
        float* wsld     = (float*)(smraw + 9216);        // [2048]
        int nb = blockIdx.x * 64;
        int ct = t & 15, nt = t >> 4;
        int rs = t >> 3, qs = t & 7;
        float acc[4][4] = {};
        for (int K0 = 0; K0 < F_IN; K0 += 32) {
            int r0 = min(nb + rs, NN - 1);
            int r1 = min(nb + rs + 32, NN - 1);
            float4 v0 = *(const float4*)&x[(size_t)r0 * F_IN + K0 + qs * 4];
            float4 v1 = *(const float4*)&x[(size_t)r1 * F_IN + K0 + qs * 4];
            *(float4*)&xs[rs][qs * 4] = v0;
            *(float4*)&xs[rs + 32][qs * 4] = v1;
            const float4* wsrc = (const float4*)&W1[(size_t)K0 * F1];
            *(float4*)&wsld[t * 4] = wsrc[t];
            *(float4*)&wsld[1024 + t * 4] = wsrc[256 + t];
            __syncthreads();
#pragma unroll 8
            for (int kk = 0; kk < 32; ++kk) {
                float4 w = *(const float4*)&wsld[kk * 64 + ct * 4];
                float x0 = xs[nt * 4 + 0][kk];
                float x1 = xs[nt * 4 + 1][kk];
                float x2 = xs[nt * 4 + 2][kk];
                float x3 = xs[nt * 4 + 3][kk];
                acc[0][0] = fmaf(x0, w.x, acc[0][0]); acc[0][1] = fmaf(x0, w.y, acc[0][1]);
                acc[0][2] = fmaf(x0, w.z, acc[0][2]); acc[0][3] = fmaf(x0, w.w, acc[0][3]);
                acc[1][0] = fmaf(x1, w.x, acc[1][0]); acc[1][1] = fmaf(x1, w.y, acc[1][1]);
                acc[1][2] = fmaf(x1, w.z, acc[1][2]); acc[1][3] = fmaf(x1, w.w, acc[1][3]);
                acc[2][0] = fmaf(x2, w.x, acc[2][0]); acc[2][1] = fmaf(x2, w.y, acc[2][1]);
                acc[2][2] = fmaf(x2, w.z, acc[2][2]); acc[2][3] = fmaf(x2, w.w, acc[2][3]);
                acc[3][0] = fmaf(x3, w.x, acc[3][0]); acc[3][1] = fmaf(x3, w.y, acc[3][1]);
                acc[3][2] = fmaf(x3, w.z, acc[3][2]); acc[3][3] = fmaf(x3, w.w, acc[3][3]);
            }
            __syncthreads();
        }
        float4 as4 = ((const float4*)a_src)[ct];
        float4 ds4 = ((const float4*)a_dst)[ct];
#pragma unroll
        for (int i = 0; i < 4; ++i) {
            int n = nb + nt * 4 + i;
            unsigned u0 = bpack(acc[i][0], acc[i][1]);
            unsigned u1 = bpack(acc[i][2], acc[i][3]);
            float ps = acc[i][0]*as4.x + acc[i][1]*as4.y + acc[i][2]*as4.z + acc[i][3]*as4.w;
            float pd = acc[i][0]*ds4.x + acc[i][1]*ds4.y + acc[i][2]*ds4.z + acc[i][3]*ds4.w;
            ps += __shfl_xor(ps, 1, 64);
            pd += __shfl_xor(pd, 1, 64);
            if (n < NN) {
                *(uint2*)&h1b[(size_t)n * 32 + ct * 2] = make_uint2(u0, u1);
                if (!(ct & 1)) {
                    as1[n * H1n + (ct >> 1)] = ps;
                    ad1[n * H1n + (ct >> 1)] = pd;
                }
            }
        }
    } else {
        int* bins  = (int*)smraw;
        int* basep = (int*)(smraw + NB * 4);
        for (int i = t; i < NB; i += 256) bins[i] = 0;
        __syncthreads();
        int pb = blockIdx.x - L1_BLOCKS;
        int e0 = pb * EPB;
        int e1 = min(e0 + EPB, E_TOT);
        for (int e = e0 + t; e < e1; e += 256) {
            int d = (e < E_BASE) ? dst[e] : (e - E_BASE);
            atomicAdd(&bins[d >> BSHIFT], 1);
        }
        __syncthreads();
        for (int i = t; i < NB; i += 256) {
            basep[i] = atomicAdd(&bucket_cnt[i], bins[i]);
            bins[i] = 0;
        }
        __syncthreads();
        for (int e = e0 + t; e < e1; e += 256) {
            int s, d;
            if (e < E_BASE) { s = src[e]; d = dst[e]; }
            else            { s = e - E_BASE; d = s; }
            int b = d >> BSHIFT;
            int p = atomicAdd(&bins[b], 1);
            store[(size_t)b * BCAP + basep[b] + p] = ((unsigned)s << 9) | (unsigned)(d & 511);
        }
    }
}

// per-bucket CSR with inline prefix over bucket_cnt
__global__ __launch_bounds__(256) void bucket_csr(const int* __restrict__ bucket_cnt,
                                                  const unsigned* __restrict__ store,
                                                  int* __restrict__ row_start,
                                                  int* __restrict__ csr_src) {
    __shared__ int cnt_l[512];
    __shared__ int incl[512];
    __shared__ int cur_l[512];
    __shared__ int sh_gbase;
    int b = blockIdx.x;
    int t = threadIdx.x;
    int cnt = bucket_cnt[b];
    int nlo = b << BSHIFT;
    int nodes = min(512, NN - nlo);
    cnt_l[t] = 0; cnt_l[t + 256] = 0;
    if (t < 64) {
        int partial = 0;
        for (int i = t; i < NB; i += 64)
            if (i < b) partial += bucket_cnt[i];
#pragma unroll
        for (int m = 1; m < 64; m <<= 1) partial += __shfl_xor(partial, m, 64);
        if (t == 0) {
            sh_gbase = partial;
            if (b == NB - 1) row_start[NN] = partial + cnt;
        }
    }
    __syncthreads();
    int gbase = sh_gbase;
    const unsigned* sp = store + (size_t)b * BCAP;
    for (int i = t; i < cnt; i += 256)
        atomicAdd(&cnt_l[sp[i] & 511], 1);
    __syncthreads();
    if (t < 64) {
        int run = 0;
        for (int c = 0; c < 512; c += 64) {
            int v = cnt_l[c + t];
#pragma unroll
            for (int off = 1; off < 64; off <<= 1) {
                int u = __shfl_up(v, off, 64);
                if (t >= off) v += u;
            }
            incl[c + t] = run + v;
            run = __shfl(run + v, 63, 64);
        }
    }
    __syncthreads();
    for (int j = t; j < 512; j += 256) {
        int start = gbase + incl[j] - cnt_l[j];
        cur_l[j] = start;
        if (j < nodes) row_start[nlo + j] = start;
    }
    __syncthreads();
    for (int i = t; i < cnt; i += 256) {
        unsigned ed = sp[i];
        int p = atomicAdd(&cur_l[ed & 511], 1);
        csr_src[p] = (int)(ed >> 9);
    }
}

// ---------------- layer 1 softmax+aggregate (R11 structure, 1 wave/block) -
__global__ void node_agg1(const int* __restrict__ row_start,
                          const int* __restrict__ csr_src,
                          const float* __restrict__ as1,
                          const float* __restrict__ ad1,
                          const unsigned* __restrict__ h1b,
                          const float* __restrict__ b1,
                          float* __restrict__ out1r) {
    int n = blockIdx.x;
    int lane = threadIdx.x;
    int e8 = lane & 7, hp = lane >> 3;        // p-phase coords
    int il = lane & 31, q = lane >> 5;        // acc coords
    int hc = il >> 2;
    float adv = ad1[(unsigned)n * 8u + (unsigned)hp];
    int lo = row_start[n], hi = row_start[n + 1];
    float ssum = 0.f, acc0 = 0.f, acc1 = 0.f;
    int   s_cur = csr_src[(unsigned)min(lo + e8, hi - 1)];
    float g_cur = as1[(unsigned)s_cur * 8u + (unsigned)hp];
    unsigned u_cur[4];
#pragma unroll
    for (int j = 0; j < 4; ++j) {
        int sb = __shfl(s_cur, 2 * j + q, 64);
        u_cur[j] = h1b[(unsigned)sb * 32u + (unsigned)il];
    }
    for (int base = lo; base < hi; base += 8) {
        int s_nxt = s_cur; float g_nxt = 0.f;
        unsigned u_nxt[4];
        bool more = (base + 8) < hi;           // wave-uniform
        if (more) {
            s_nxt = csr_src[(unsigned)min(base + 8 + e8, hi - 1)];
            g_nxt = as1[(unsigned)s_nxt * 8u + (unsigned)hp];
#pragma unroll
            for (int j = 0; j < 4; ++j) {
                int sb = __shfl(s_nxt, 2 * j + q, 64);
                u_nxt[j] = h1b[(unsigned)sb * 32u + (unsigned)il];
            }
        }
        float v = lrelu(g_cur + adv);
        float p = (base + e8 < hi) ? __expf(v) : 0.f;
        ssum += p;
#pragma unroll
        for (int j = 0; j < 4; ++j) {
            float pb = __shfl(p, (hc << 3) | (2 * j + q), 64);
            acc0 = fmaf(pb, blo(u_cur[j]), acc0);
            acc1 = fmaf(pb, bhi(u_cur[j]), acc1);
        }
        s_cur = s_nxt; g_cur = g_nxt;
#pragma unroll
        for (int j = 0; j < 4; ++j) u_cur[j] = u_nxt[j];
    }
    ssum += __shfl_xor(ssum, 1, 64);
    ssum += __shfl_xor(ssum, 2, 64);
    ssum += __shfl_xor(ssum, 4, 64);
    float sh = __shfl(ssum, hc << 3, 64);
    float p0 = acc0 + __shfl(acc0, il | 32, 64);
    float p1 = acc1 + __shfl(acc1, il | 32, 64);
    if (lane < 32) {
        float r = 1.f / (sh + 1e-16f);
        float2 bv = ((const float2*)b1)[il];
        float2 o;
        o.x = fmaxf(fmaf(p0, r, bv.x), 0.f);
        o.y = fmaxf(fmaf(p1, r, bv.y), 0.f);
        ((float2*)(out1r + (size_t)n * F1))[il] = o;
    }
}

// ---------------- layer 2 GEMM: h2a + 32B h2cx rows (as2 embedded) --------
__global__ __launch_bounds__(256) void linear2(const float* __restrict__ out1r,
                                               const float* __restrict__ W2,
                                               const float* __restrict__ a_src2,
                                               const float* __restrict__ a_dst2,
                                               unsigned* __restrict__ h2a,
                                               unsigned* __restrict__ h2cx,
                                               float* __restrict__ ad2) {
    __shared__ float xs[128][65];
    __shared__ float ws[64 * 40];
    int t = threadIdx.x;
    int nb = blockIdx.x * 128;
    int colq = t & 15, rr = t >> 4;
#pragma unroll
    for (int i = 0; i < 8; ++i) {
        int r = rr + 16 * i;
        int g = min(nb + r, NN - 1);
        float4 v = *(const float4*)&out1r[(size_t)g * F1 + colq * 4];
        xs[r][colq * 4 + 0] = v.x; xs[r][colq * 4 + 1] = v.y;
        xs[r][colq * 4 + 2] = v.z; xs[r][colq * 4 + 3] = v.w;
    }
#pragma unroll
    for (int i = 0; i < 10; ++i) ws[t + 256 * i] = W2[t + 256 * i];
    __syncthreads();
    int ct = t & 7, nt = t >> 3;
    float acc[4][5] = {};
#pragma unroll 4
    for (int k = 0; k < F1; ++k) {
        float w0 = ws[k * 40 + ct * 5 + 0];
        float w1 = ws[k * 40 + ct * 5 + 1];
        float w2 = ws[k * 40 + ct * 5 + 2];
        float w3 = ws[k * 40 + ct * 5 + 3];
        float w4 = ws[k * 40 + ct * 5 + 4];
#pragma unroll
        for (int i = 0; i < 4; ++i) {
            float xv = xs[nt * 4 + i][k];
            acc[i][0] = fmaf(xv, w0, acc[i][0]);
            acc[i][1] = fmaf(xv, w1, acc[i][1]);
            acc[i][2] = fmaf(xv, w2, acc[i][2]);
            acc[i][3] = fmaf(xv, w3, acc[i][3]);
            acc[i][4] = fmaf(xv, w4, acc[i][4]);
        }
    }
    float aw[5], dw[5];
#pragma unroll
    for (int j = 0; j < 5; ++j) { aw[j] = a_src2[ct * 5 + j]; dw[j] = a_dst2[ct * 5 + j]; }
#pragma unroll
    for (int i = 0; i < 4; ++i) {
        int n = nb + nt * 4 + i;
        float vs = acc[i][0]*aw[0] + acc[i][1]*aw[1] + acc[i][2]*aw[2]
                 + acc[i][3]*aw[3] + acc[i][4]*aw[4];
        float vd = acc[i][0]*dw[0] + acc[i][1]*dw[1] + acc[i][2]*dw[2]
                 + acc[i][3]*dw[3] + acc[i][4]*dw[4];
        vs += __shfl_xor(vs, 1, 64); vs += __shfl_xor(vs, 2, 64); vs += __shfl_xor(vs, 4, 64);
        vd += __shfl_xor(vd, 1, 64); vd += __shfl_xor(vd, 2, 64); vd += __shfl_xor(vd, 4, 64);
        if (n < NN && ct == 0) {
            ad2[n] = vd;
            h2cx[(size_t)n * 8 + 4] = __float_as_uint(vs);   // as2 embedded in row
        }
    }
    __syncthreads();
#pragma unroll
    for (int i = 0; i < 4; ++i) {
        int r = nt * 4 + i;
#pragma unroll
        for (int j = 0; j < 5; ++j) xs[r][ct * 5 + j] = acc[i][j];
    }
    __syncthreads();
    {
        int r = t >> 1, half = t & 1;
        int n = nb + r;
        if (n < NN) {
#pragma unroll
            for (int k = 0; k < 10; ++k) {
                int w = half * 10 + k;
                unsigned val = bpack(xs[r][2 * w], xs[r][2 * w + 1]);
                if (w < 16) h2a[(size_t)n * 16 + w] = val;
                else        h2cx[(size_t)n * 8 + (w - 16)] = val;
            }
        }
    }
}

// ---------------- layer 2 softmax+aggregate (+b2) -------------------------
// R11 1-wave structure; as2 read from the h2cx row (same sector as acc-phase
// h2c reads — one fewer random L2 request per edge).
__global__ void node_agg2(const int* __restrict__ row_start,
                          const int* __restrict__ csr_src,
                          const float* __restrict__ ad2,
                          const unsigned* __restrict__ h2,
                          const float* __restrict__ b2,
                          float* __restrict__ out) {
    int n = blockIdx.x;
    int lane = threadIdx.x;
    int e8 = lane & 7;
    int il = lane & 31, q = lane >> 5;
    bool act = il < 20;
    unsigned gstride = (il < 16) ? 16u : ((il < 20) ? 8u : 0u);
    unsigned gofs    = (il < 16) ? (unsigned)il
                     : ((il < 20) ? (HC_BASE + (unsigned)(il - 16)) : HC_BASE + 4u);
    float adv = ad2[n];
    int lo = row_start[n], hi = row_start[n + 1];
    float ssum = 0.f, acc0 = 0.f, acc1 = 0.f;
    int   s_cur = csr_src[(unsigned)min(lo + e8, hi - 1)];
    float g_cur = __uint_as_float(h2[HC_BASE + (unsigned)s_cur * 8u + 4u]);
    unsigned u_cur[4];
#pragma unroll
    for (int j = 0; j < 4; ++j) {
        int sb = __shfl(s_cur, 2 * j + q, 64);
        u_cur[j] = h2[(unsigned)sb * gstride + gofs];
    }
    for (int base = lo; base < hi; base += 8) {
        int s_nxt = s_cur; float g_nxt = 0.f;
        unsigned u_nxt[4];
        bool more = (base + 8) < hi;           // wave-uniform
        if (more) {
            s_nxt = csr_src[(unsigned)min(base + 8 + e8, hi - 1)];
            g_nxt = __uint_as_float(h2[HC_BASE + (unsigned)s_nxt * 8u + 4u]);
#pragma unroll
            for (int j = 0; j < 4; ++j) {
                int sb = __shfl(s_nxt, 2 * j + q, 64);
                u_nxt[j] = h2[(unsigned)sb * gstride + gofs];
            }
        }
        float v = lrelu(g_cur + adv);
        float p = (base + e8 < hi) ? __expf(v) : 0.f;
        ssum += p;
#pragma unroll
        for (int j = 0; j < 4; ++j) {
            float pb = __shfl(p, 2 * j + q, 64);
            acc0 = fmaf(pb, blo(u_cur[j]), acc0);
            acc1 = fmaf(pb, bhi(u_cur[j]), acc1);
        }
        s_cur = s_nxt; g_cur = g_nxt;
#pragma unroll
        for (int j = 0; j < 4; ++j) u_cur[j] = u_nxt[j];
    }
    ssum += __shfl_xor(ssum, 1, 64);
    ssum += __shfl_xor(ssum, 2, 64);
    ssum += __shfl_xor(ssum, 4, 64);
    float p0 = acc0 + __shfl(acc0, il | 32, 64);
    float p1 = acc1 + __shfl(acc1, il | 32, 64);
    if (lane < 32 && act) {
        float r = 1.f / (ssum + 1e-16f);
        float2 bv = ((const float2*)b2)[il];
        float2 o;
        o.x = fmaf(p0, r, bv.x);
        o.y = fmaf(p1, r, bv.y);
        ((float2*)(out + (size_t)n * F2))[il] = o;
    }
}

extern "C" void kernel_launch(void* const* d_in, const int* in_sizes, int n_in,
                              void* d_out, int out_size, void* d_ws, size_t ws_size,
                              hipStream_t stream) {
    const float* x      = (const float*)d_in[0];
    const int*   ei     = (const int*)d_in[1];
    const float* W1     = (const float*)d_in[2];
    const float* a_src1 = (const float*)d_in[3];
    const float* a_dst1 = (const float*)d_in[4];
    const float* b1     = (const float*)d_in[5];
    const float* W2     = (const float*)d_in[6];
    const float* a_src2 = (const float*)d_in[7];
    const float* a_dst2 = (const float*)d_in[8];
    const float* b2     = (const float*)d_in[9];
    float* out = (float*)d_out;
    const int* srcp = ei;            // edge_index[0]
    const int* dstp = ei + E_BASE;   // edge_index[1]

    unsigned* h1b        = (unsigned*)d_ws;                      // N*32 uints
    unsigned* storeu     = h1b + (size_t)NN * 32;                // NB*BCAP uints
    float*    as1        = (float*)(storeu + (size_t)NB * BCAP); // N*8
    float*    ad1        = as1 + (size_t)NN * H1n;               // N*8
    float*    out1r      = ad1 + (size_t)NN * H1n;               // N*64
    unsigned* h2a        = (unsigned*)(out1r + (size_t)NN * F1); // N*16 uints
    unsigned* h2cx       = h2a + (size_t)NN * 16;                // N*8 uints (32B rows, as2@word4)
    float*    ad2        = (float*)(h2cx + (size_t)NN * 8);      // N
    int*      row_start  = (int*)(ad2 + NN);                     // N+1
    int*      csr_src    = row_start + (NN + 1);                 // E_TOT
    int*      bucket_cnt = csr_src + E_TOT;                      // NB

    hipMemsetAsync(bucket_cnt, 0, NB * sizeof(int), stream);

    fused_l1p<<<L1_BLOCKS + P1_BLOCKS, 256, 0, stream>>>(
        x, W1, a_src1, a_dst1, h1b, as1, ad1, srcp, dstp, bucket_cnt, storeu);
    bucket_csr<<<NB, 256, 0, stream>>>(bucket_cnt, storeu, row_start, csr_src);

    node_agg1<<<NN, 64, 0, stream>>>(row_start, csr_src, as1, ad1, h1b, b1, out1r);

    linear2<<<(NN + 127) / 128, 256, 0, stream>>>(out1r, W2, a_src2, a_dst2, h2a, h2cx, ad2);
    node_agg2<<<NN, 64, 0, stream>>>(row_start, csr_src, ad2, h2a, b2, out);
}

// Round 15
// 187.725 us; speedup vs baseline: 1.0290x; 1.0184x over previous
//
#include <hip/hip_runtime.h>
#include <math.h>

constexpr int NN     = 100000;
constexpr int E_BASE = 1600000;
constexpr int E_TOT  = E_BASE + NN;   // self-loops appended
constexpr int F_IN   = 128;
constexpr int F1     = 64;            // H1*C1
constexpr int H1n    = 8;
constexpr int F2     = 40;            // layer-2 out (H=1)

// bucketed CSR build geometry
constexpr int BSHIFT    = 9;                      // 512 nodes per bucket
constexpr int NB        = (NN + 511) >> BSHIFT;   // 196 buckets
constexpr int BCAP      = 12288;
constexpr int P1_BLOCKS = 256;
constexpr int EPB       = (E_TOT + P1_BLOCKS - 1) / P1_BLOCKS;   // 6641
constexpr int L1_BLOCKS = (NN + 63) / 64;                        // 1563

__device__ __forceinline__ float lrelu(float v) { return fmaxf(v, 0.2f * v); }

__device__ __forceinline__ unsigned bpack(float a, float b) {
    unsigned ua = __float_as_uint(a) + 0x8000u;
    unsigned ub = __float_as_uint(b) + 0x8000u;
    return (ua >> 16) | (ub & 0xFFFF0000u);
}
__device__ __forceinline__ float blo(unsigned u) { return __uint_as_float(u << 16); }
__device__ __forceinline__ float bhi(unsigned u) { return __uint_as_float(u & 0xFFFF0000u); }

// ---------------- fused: layer-1 GEMM (+logits) ∪ edge partition ----------
__global__ __launch_bounds__(256) void fused_l1p(const float* __restrict__ x,
                                                 const float* __restrict__ W1,
                                                 const float* __restrict__ a_src,
                                                 const float* __restrict__ a_dst,
                                                 unsigned* __restrict__ h1b,
                                                 float* __restrict__ as1,
                                                 float* __restrict__ ad1,
                                                 const int* __restrict__ src,
                                                 const int* __restrict__ dst,
                                                 int* __restrict__ bucket_cnt,
                                                 unsigned* __restrict__ store) {
    __shared__ __align__(16) unsigned char smraw[17408];
    int t = threadIdx.x;
    if (blockIdx.x < L1_BLOCKS) {
        float (*xs)[36] = (float(*)[36])smraw;           // [64][36]
        float* wsld     = (float*)(smraw + 9216);        // [2048]
        int nb = blockIdx.x * 64;
        int ct = t & 15, nt = t >> 4;
        int rs = t >> 3, qs = t & 7;
        float acc[4][4] = {};
        for (int K0 = 0; K0 < F_IN; K0 += 32) {
            int r0 = min(nb + rs, NN - 1);
            int r1 = min(nb + rs + 32, NN - 1);
            float4 v0 = *(const float4*)&x[(size_t)r0 * F_IN + K0 + qs * 4];
            float4 v1 = *(const float4*)&x[(size_t)r1 * F_IN + K0 + qs * 4];
            *(float4*)&xs[rs][qs * 4] = v0;
            *(float4*)&xs[rs + 32][qs * 4] = v1;
            const float4* wsrc = (const float4*)&W1[(size_t)K0 * F1];
            *(float4*)&wsld[t * 4] = wsrc[t];
            *(float4*)&wsld[1024 + t * 4] = wsrc[256 + t];
            __syncthreads();
#pragma unroll 8
            for (int kk = 0; kk < 32; ++kk) {
                float4 w = *(const float4*)&wsld[kk * 64 + ct * 4];
                float x0 = xs[nt * 4 + 0][kk];
                float x1 = xs[nt * 4 + 1][kk];
                float x2 = xs[nt * 4 + 2][kk];
                float x3 = xs[nt * 4 + 3][kk];
                acc[0][0] = fmaf(x0, w.x, acc[0][0]); acc[0][1] = fmaf(x0, w.y, acc[0][1]);
                acc[0][2] = fmaf(x0, w.z, acc[0][2]); acc[0][3] = fmaf(x0, w.w, acc[0][3]);
                acc[1][0] = fmaf(x1, w.x, acc[1][0]); acc[1][1] = fmaf(x1, w.y, acc[1][1]);
                acc[1][2] = fmaf(x1, w.z, acc[1][2]); acc[1][3] = fmaf(x1, w.w, acc[1][3]);
                acc[2][0] = fmaf(x2, w.x, acc[2][0]); acc[2][1] = fmaf(x2, w.y, acc[2][1]);
                acc[2][2] = fmaf(x2, w.z, acc[2][2]); acc[2][3] = fmaf(x2, w.w, acc[2][3]);
                acc[3][0] = fmaf(x3, w.x, acc[3][0]); acc[3][1] = fmaf(x3, w.y, acc[3][1]);
                acc[3][2] = fmaf(x3, w.z, acc[3][2]); acc[3][3] = fmaf(x3, w.w, acc[3][3]);
            }
            __syncthreads();
        }
        float4 as4 = ((const float4*)a_src)[ct];
        float4 ds4 = ((const float4*)a_dst)[ct];
#pragma unroll
        for (int i = 0; i < 4; ++i) {
            int n = nb + nt * 4 + i;
            unsigned u0 = bpack(acc[i][0], acc[i][1]);
            unsigned u1 = bpack(acc[i][2], acc[i][3]);
            float ps = acc[i][0]*as4.x + acc[i][1]*as4.y + acc[i][2]*as4.z + acc[i][3]*as4.w;
            float pd = acc[i][0]*ds4.x + acc[i][1]*ds4.y + acc[i][2]*ds4.z + acc[i][3]*ds4.w;
            ps += __shfl_xor(ps, 1, 64);
            pd += __shfl_xor(pd, 1, 64);
            if (n < NN) {
                *(uint2*)&h1b[(size_t)n * 32 + ct * 2] = make_uint2(u0, u1);
                if (!(ct & 1)) {
                    as1[n * H1n + (ct >> 1)] = ps;
                    ad1[n * H1n + (ct >> 1)] = pd;
                }
            }
        }
    } else {
        int* bins  = (int*)smraw;
        int* basep = (int*)(smraw + NB * 4);
        for (int i = t; i < NB; i += 256) bins[i] = 0;
        __syncthreads();
        int pb = blockIdx.x - L1_BLOCKS;
        int e0 = pb * EPB;
        int e1 = min(e0 + EPB, E_TOT);
        for (int e = e0 + t; e < e1; e += 256) {
            int d = (e < E_BASE) ? dst[e] : (e - E_BASE);
            atomicAdd(&bins[d >> BSHIFT], 1);
        }
        __syncthreads();
        for (int i = t; i < NB; i += 256) {
            basep[i] = atomicAdd(&bucket_cnt[i], bins[i]);
            bins[i] = 0;
        }
        __syncthreads();
        for (int e = e0 + t; e < e1; e += 256) {
            int s, d;
            if (e < E_BASE) { s = src[e]; d = dst[e]; }
            else            { s = e - E_BASE; d = s; }
            int b = d >> BSHIFT;
            int p = atomicAdd(&bins[b], 1);
            store[(size_t)b * BCAP + basep[b] + p] = ((unsigned)s << 9) | (unsigned)(d & 511);
        }
    }
}

// per-bucket CSR with inline prefix over bucket_cnt
__global__ __launch_bounds__(256) void bucket_csr(const int* __restrict__ bucket_cnt,
                                                  const unsigned* __restrict__ store,
                                                  int* __restrict__ row_start,
                                                  int* __restrict__ csr_src) {
    __shared__ int cnt_l[512];
    __shared__ int incl[512];
    __shared__ int cur_l[512];
    __shared__ int sh_gbase;
    int b = blockIdx.x;
    int t = threadIdx.x;
    int cnt = bucket_cnt[b];
    int nlo = b << BSHIFT;
    int nodes = min(512, NN - nlo);
    cnt_l[t] = 0; cnt_l[t + 256] = 0;
    if (t < 64) {
        int partial = 0;
        for (int i = t; i < NB; i += 64)
            if (i < b) partial += bucket_cnt[i];
#pragma unroll
        for (int m = 1; m < 64; m <<= 1) partial += __shfl_xor(partial, m, 64);
        if (t == 0) {
            sh_gbase = partial;
            if (b == NB - 1) row_start[NN] = partial + cnt;
        }
    }
    __syncthreads();
    int gbase = sh_gbase;
    const unsigned* sp = store + (size_t)b * BCAP;
    for (int i = t; i < cnt; i += 256)
        atomicAdd(&cnt_l[sp[i] & 511], 1);
    __syncthreads();
    if (t < 64) {
        int run = 0;
        for (int c = 0; c < 512; c += 64) {
            int v = cnt_l[c + t];
#pragma unroll
            for (int off = 1; off < 64; off <<= 1) {
                int u = __shfl_up(v, off, 64);
                if (t >= off) v += u;
            }
            incl[c + t] = run + v;
            run = __shfl(run + v, 63, 64);
        }
    }
    __syncthreads();
    for (int j = t; j < 512; j += 256) {
        int start = gbase + incl[j] - cnt_l[j];
        cur_l[j] = start;
        if (j < nodes) row_start[nlo + j] = start;
    }
    __syncthreads();
    for (int i = t; i < cnt; i += 256) {
        unsigned ed = sp[i];
        int p = atomicAdd(&cur_l[ed & 511], 1);
        csr_src[p] = (int)(ed >> 9);
    }
}

// ---------------- layer 1 softmax+aggregate -------------------------------
// 1 wave/block. Deep pipeline: next chunk's {csr, logit, 4 h1b rows} issued
// before current chunk's exp/shuffle/FMA. 32-bit offsets throughout.
__global__ void node_agg1(const int* __restrict__ row_start,
                          const int* __restrict__ csr_src,
                          const float* __restrict__ as1,
                          const float* __restrict__ ad1,
                          const unsigned* __restrict__ h1b,
                          const float* __restrict__ b1,
                          float* __restrict__ out1r) {
    int n = blockIdx.x;
    int lane = threadIdx.x;
    int e8 = lane & 7, hp = lane >> 3;        // p-phase coords
    int il = lane & 31, q = lane >> 5;        // acc coords
    int hc = il >> 2;
    float adv = ad1[(unsigned)n * 8u + (unsigned)hp];
    int lo = row_start[n], hi = row_start[n + 1];
    float ssum = 0.f, acc0 = 0.f, acc1 = 0.f;
    // prologue: chunk 0 loads
    int   s_cur = csr_src[(unsigned)min(lo + e8, hi - 1)];
    float g_cur = as1[(unsigned)s_cur * 8u + (unsigned)hp];
    unsigned u_cur[4];
#pragma unroll
    for (int j = 0; j < 4; ++j) {
        int sb = __shfl(s_cur, 2 * j + q, 64);
        u_cur[j] = h1b[(unsigned)sb * 32u + (unsigned)il];
    }
    for (int base = lo; base < hi; base += 8) {
        int s_nxt = s_cur; float g_nxt = 0.f;
        unsigned u_nxt[4];
        bool more = (base + 8) < hi;           // wave-uniform
        if (more) {
            s_nxt = csr_src[(unsigned)min(base + 8 + e8, hi - 1)];
            g_nxt = as1[(unsigned)s_nxt * 8u + (unsigned)hp];
#pragma unroll
            for (int j = 0; j < 4; ++j) {
                int sb = __shfl(s_nxt, 2 * j + q, 64);
                u_nxt[j] = h1b[(unsigned)sb * 32u + (unsigned)il];
            }
        }
        float v = lrelu(g_cur + adv);
        float p = (base + e8 < hi) ? __expf(v) : 0.f;
        ssum += p;
#pragma unroll
        for (int j = 0; j < 4; ++j) {
            float pb = __shfl(p, (hc << 3) | (2 * j + q), 64);
            acc0 = fmaf(pb, blo(u_cur[j]), acc0);
            acc1 = fmaf(pb, bhi(u_cur[j]), acc1);
        }
        s_cur = s_nxt; g_cur = g_nxt;
#pragma unroll
        for (int j = 0; j < 4; ++j) u_cur[j] = u_nxt[j];
    }
    ssum += __shfl_xor(ssum, 1, 64);
    ssum += __shfl_xor(ssum, 2, 64);
    ssum += __shfl_xor(ssum, 4, 64);
    float sh = __shfl(ssum, hc << 3, 64);
    float p0 = acc0 + __shfl(acc0, il | 32, 64);
    float p1 = acc1 + __shfl(acc1, il | 32, 64);
    if (lane < 32) {
        float r = 1.f / (sh + 1e-16f);
        float2 bv = ((const float2*)b1)[il];
        float2 o;
        o.x = fmaxf(fmaf(p0, r, bv.x), 0.f);
        o.y = fmaxf(fmaf(p1, r, bv.y), 0.f);
        ((float2*)(out1r + (size_t)n * F1))[il] = o;
    }
}

// ---------------- layer 2 GEMM: h2a/h2c(bf16) = out1r @ W2, fused logits --
__global__ __launch_bounds__(256) void linear2(const float* __restrict__ out1r,
                                               const float* __restrict__ W2,
                                               const float* __restrict__ a_src2,
                                               const float* __restrict__ a_dst2,
                                               unsigned* __restrict__ h2a,
                                               unsigned* __restrict__ h2c,
                                               float* __restrict__ as2,
                                               float* __restrict__ ad2) {
    __shared__ float xs[128][65];
    __shared__ float ws[64 * 40];
    int t = threadIdx.x;
    int nb = blockIdx.x * 128;
    int colq = t & 15, rr = t >> 4;
#pragma unroll
    for (int i = 0; i < 8; ++i) {
        int r = rr + 16 * i;
        int g = min(nb + r, NN - 1);
        float4 v = *(const float4*)&out1r[(size_t)g * F1 + colq * 4];
        xs[r][colq * 4 + 0] = v.x; xs[r][colq * 4 + 1] = v.y;
        xs[r][colq * 4 + 2] = v.z; xs[r][colq * 4 + 3] = v.w;
    }
#pragma unroll
    for (int i = 0; i < 10; ++i) ws[t + 256 * i] = W2[t + 256 * i];
    __syncthreads();
    int ct = t & 7, nt = t >> 3;
    float acc[4][5] = {};
#pragma unroll 4
    for (int k = 0; k < F1; ++k) {
        float w0 = ws[k * 40 + ct * 5 + 0];
        float w1 = ws[k * 40 + ct * 5 + 1];
        float w2 = ws[k * 40 + ct * 5 + 2];
        float w3 = ws[k * 40 + ct * 5 + 3];
        float w4 = ws[k * 40 + ct * 5 + 4];
#pragma unroll
        for (int i = 0; i < 4; ++i) {
            float xv = xs[nt * 4 + i][k];
            acc[i][0] = fmaf(xv, w0, acc[i][0]);
            acc[i][1] = fmaf(xv, w1, acc[i][1]);
            acc[i][2] = fmaf(xv, w2, acc[i][2]);
            acc[i][3] = fmaf(xv, w3, acc[i][3]);
            acc[i][4] = fmaf(xv, w4, acc[i][4]);
        }
    }
    float aw[5], dw[5];
#pragma unroll
    for (int j = 0; j < 5; ++j) { aw[j] = a_src2[ct * 5 + j]; dw[j] = a_dst2[ct * 5 + j]; }
#pragma unroll
    for (int i = 0; i < 4; ++i) {
        int n = nb + nt * 4 + i;
        float vs = acc[i][0]*aw[0] + acc[i][1]*aw[1] + acc[i][2]*aw[2]
                 + acc[i][3]*aw[3] + acc[i][4]*aw[4];
        float vd = acc[i][0]*dw[0] + acc[i][1]*dw[1] + acc[i][2]*dw[2]
                 + acc[i][3]*dw[3] + acc[i][4]*dw[4];
        vs += __shfl_xor(vs, 1, 64); vs += __shfl_xor(vs, 2, 64); vs += __shfl_xor(vs, 4, 64);
        vd += __shfl_xor(vd, 1, 64); vd += __shfl_xor(vd, 2, 64); vd += __shfl_xor(vd, 4, 64);
        if (n < NN && ct == 0) { as2[n] = vs; ad2[n] = vd; }
    }
    __syncthreads();
#pragma unroll
    for (int i = 0; i < 4; ++i) {
        int r = nt * 4 + i;
#pragma unroll
        for (int j = 0; j < 5; ++j) xs[r][ct * 5 + j] = acc[i][j];
    }
    __syncthreads();
    {
        int r = t >> 1, half = t & 1;
        int n = nb + r;
        if (n < NN) {
#pragma unroll
            for (int k = 0; k < 10; ++k) {
                int w = half * 10 + k;
                unsigned val = bpack(xs[r][2 * w], xs[r][2 * w + 1]);
                if (w < 16) h2a[(size_t)n * 16 + w] = val;
                else        h2c[(size_t)n * 4 + (w - 16)] = val;
            }
        }
    }
}

// ---------------- layer 2 softmax+aggregate (+b2) -------------------------
// 1 wave/block; deep pipeline like node_agg1; uniform h2 base + 32-bit
// per-lane offset (h2a/h2c contiguous).
__global__ void node_agg2(const int* __restrict__ row_start,
                          const int* __restrict__ csr_src,
                          const float* __restrict__ as2,
                          const float* __restrict__ ad2,
                          const unsigned* __restrict__ h2,
                          const float* __restrict__ b2,
                          float* __restrict__ out) {
    int n = blockIdx.x;
    int lane = threadIdx.x;
    int e8 = lane & 7;
    int il = lane & 31, q = lane >> 5;
    bool act = il < 20;
    unsigned gstride = (il < 16) ? 16u : ((il < 20) ? 4u : 0u);
    unsigned gofs    = (il < 16) ? (unsigned)il
                     : ((il < 20) ? (unsigned)(NN * 16 + (il - 16)) : 0u);
    float adv = ad2[n];
    int lo = row_start[n], hi = row_start[n + 1];
    float ssum = 0.f, acc0 = 0.f, acc1 = 0.f;
    int   s_cur = csr_src[(unsigned)min(lo + e8, hi - 1)];
    float g_cur = as2[(unsigned)s_cur];
    unsigned u_cur[4];
#pragma unroll
    for (int j = 0; j < 4; ++j) {
        int sb = __shfl(s_cur, 2 * j + q, 64);
        u_cur[j] = h2[(unsigned)sb * gstride + gofs];
    }
    for (int base = lo; base < hi; base += 8) {
        int s_nxt = s_cur; float g_nxt = 0.f;
        unsigned u_nxt[4];
        bool more = (base + 8) < hi;           // wave-uniform
        if (more) {
            s_nxt = csr_src[(unsigned)min(base + 8 + e8, hi - 1)];
            g_nxt = as2[(unsigned)s_nxt];
#pragma unroll
            for (int j = 0; j < 4; ++j) {
                int sb = __shfl(s_nxt, 2 * j + q, 64);
                u_nxt[j] = h2[(unsigned)sb * gstride + gofs];
            }
        }
        float v = lrelu(g_cur + adv);
        float p = (base + e8 < hi) ? __expf(v) : 0.f;
        ssum += p;
#pragma unroll
        for (int j = 0; j < 4; ++j) {
            float pb = __shfl(p, 2 * j + q, 64);
            acc0 = fmaf(pb, blo(u_cur[j]), acc0);
            acc1 = fmaf(pb, bhi(u_cur[j]), acc1);
        }
        s_cur = s_nxt; g_cur = g_nxt;
#pragma unroll
        for (int j = 0; j < 4; ++j) u_cur[j] = u_nxt[j];
    }
    ssum += __shfl_xor(ssum, 1, 64);
    ssum += __shfl_xor(ssum, 2, 64);
    ssum += __shfl_xor(ssum, 4, 64);
    float p0 = acc0 + __shfl(acc0, il | 32, 64);
    float p1 = acc1 + __shfl(acc1, il | 32, 64);
    if (lane < 32 && act) {
        float r = 1.f / (ssum + 1e-16f);
        float2 bv = ((const float2*)b2)[il];
        float2 o;
        o.x = fmaf(p0, r, bv.x);
        o.y = fmaf(p1, r, bv.y);
        ((float2*)(out + (size_t)n * F2))[il] = o;
    }
}

extern "C" void kernel_launch(void* const* d_in, const int* in_sizes, int n_in,
                              void* d_out, int out_size, void* d_ws, size_t ws_size,
                              hipStream_t stream) {
    const float* x      = (const float*)d_in[0];
    const int*   ei     = (const int*)d_in[1];
    const float* W1     = (const float*)d_in[2];
    const float* a_src1 = (const float*)d_in[3];
    const float* a_dst1 = (const float*)d_in[4];
    const float* b1     = (const float*)d_in[5];
    const float* W2     = (const float*)d_in[6];
    const float* a_src2 = (const float*)d_in[7];
    const float* a_dst2 = (const float*)d_in[8];
    const float* b2     = (const float*)d_in[9];
    float* out = (float*)d_out;
    const int* srcp = ei;            // edge_index[0]
    const int* dstp = ei + E_BASE;   // edge_index[1]

    unsigned* h1b        = (unsigned*)d_ws;                      // N*32 uints
    unsigned* storeu     = h1b + (size_t)NN * 32;                // NB*BCAP uints
    float*    as1        = (float*)(storeu + (size_t)NB * BCAP); // N*8
    float*    ad1        = as1 + (size_t)NN * H1n;               // N*8
    float*    out1r      = ad1 + (size_t)NN * H1n;               // N*64
    unsigned* h2a        = (unsigned*)(out1r + (size_t)NN * F1); // N*16 uints
    unsigned* h2c        = h2a + (size_t)NN * 16;                // N*4 uints (contiguous)
    float*    as2        = (float*)(h2c + (size_t)NN * 4);       // N
    float*    ad2        = as2 + NN;                             // N
    int*      row_start  = (int*)(ad2 + NN);                     // N+1
    int*      csr_src    = row_start + (NN + 1);                 // E_TOT
    int*      bucket_cnt = csr_src + E_TOT;                      // NB

    hipMemsetAsync(bucket_cnt, 0, NB * sizeof(int), stream);

    fused_l1p<<<L1_BLOCKS + P1_BLOCKS, 256, 0, stream>>>(
        x, W1, a_src1, a_dst1, h1b, as1, ad1, srcp, dstp, bucket_cnt, storeu);
    bucket_csr<<<NB, 256, 0, stream>>>(bucket_cnt, storeu, row_start, csr_src);

    node_agg1<<<NN, 64, 0, stream>>>(row_start, csr_src, as1, ad1, h1b, b1, out1r);

    linear2<<<(NN + 127) / 128, 256, 0, stream>>>(out1r, W2, a_src2, a_dst2, h2a, h2c, as2, ad2);
    node_agg2<<<NN, 64, 0, stream>>>(row_start, csr_src, as2, ad2, h2a, b2, out);
}